// Round 7
// baseline (1649.141 us; speedup 1.0000x reference)
//
#include <hip/hip_runtime.h>

#define D 128

typedef short v8s __attribute__((ext_vector_type(8)));
typedef float v4f __attribute__((ext_vector_type(4)));

// fp32 -> bf16 hi/lo split: f ~= hi + lo, |err| ~ 2^-17 * |f|
__device__ __forceinline__ void f2hl(float f, unsigned short& h, unsigned short& l) {
    unsigned int u = __float_as_uint(f);
    unsigned int hu = u & 0xffff0000u;
    float lf = f - __uint_as_float(hu);          // exact
    h = (unsigned short)(hu >> 16);
    l = (unsigned short)((__float_as_uint(lf) + 0x8000u) >> 16);  // round
}

// permuted column position for a 4-aligned k chunk (MFMA A-frag contiguous layout)
// k = 4g + (e&3) + 16*(e>>2)  <->  p = 8g + e   (within each 32-wide k block)
__device__ __forceinline__ int permc(int c) {
    return (c & ~31) + ((c & 12) << 1) + ((c & 16) >> 2);
}

// ---------------- preprocessing ----------------

__global__ void k_count(const int* __restrict__ dst, int* __restrict__ deg, int E) {
    int e = blockIdx.x * 256 + threadIdx.x;
    if (e < E) atomicAdd(&deg[dst[e]], 1);
}

__global__ __launch_bounds__(256) void k_blocksum(const int* __restrict__ deg,
                                                  int* __restrict__ bsums, int N) {
    __shared__ int s[256];
    int base = blockIdx.x * 1024 + threadIdx.x * 4;
    int v = 0;
#pragma unroll
    for (int j = 0; j < 4; ++j) { int i = base + j; if (i < N) v += deg[i]; }
    s[threadIdx.x] = v;
    __syncthreads();
    for (int off = 128; off > 0; off >>= 1) {
        if (threadIdx.x < off) s[threadIdx.x] += s[threadIdx.x + off];
        __syncthreads();
    }
    if (threadIdx.x == 0) bsums[blockIdx.x] = s[0];
}

__global__ __launch_bounds__(256) void k_scanbsums(int* __restrict__ bsums, int NB) {
    __shared__ int s[256];
    __shared__ int carry;
    int t = threadIdx.x;
    if (t == 0) carry = 0;
    __syncthreads();
    for (int base = 0; base < NB; base += 256) {
        int i = base + t;
        int v = (i < NB) ? bsums[i] : 0;
        s[t] = v;
        __syncthreads();
        for (int off = 1; off < 256; off <<= 1) {
            int x = (t >= off) ? s[t - off] : 0;
            __syncthreads();
            s[t] += x;
            __syncthreads();
        }
        if (i < NB) bsums[i] = carry + s[t] - v;   // exclusive
        __syncthreads();
        if (t == 0) carry += s[255];
        __syncthreads();
    }
}

__global__ __launch_bounds__(256) void k_scan2(const int* __restrict__ deg,
                                               const int* __restrict__ bsums,
                                               int* __restrict__ rowst,
                                               float* __restrict__ dinv, int N) {
    __shared__ int s[256];
    int t = threadIdx.x;
    int base = blockIdx.x * 1024 + t * 4;
    int v[4];
#pragma unroll
    for (int j = 0; j < 4; ++j) { int i = base + j; v[j] = (i < N) ? deg[i] : 0; }
    int tsum = v[0] + v[1] + v[2] + v[3];
    s[t] = tsum;
    __syncthreads();
    for (int off = 1; off < 256; off <<= 1) {
        int x = (t >= off) ? s[t - off] : 0;
        __syncthreads();
        s[t] += x;
        __syncthreads();
    }
    int run = s[t] - tsum + bsums[blockIdx.x];
#pragma unroll
    for (int j = 0; j < 4; ++j) {
        int i = base + j;
        if (i < N) {
            rowst[i] = run;
            dinv[i] = rsqrtf((float)(v[j] + 1));   // +1 for self-loop
        }
        run += v[j];
    }
}

__global__ void k_fill(const int* __restrict__ src, const int* __restrict__ dst,
                       const int* __restrict__ rowst, int* __restrict__ cursor,
                       const float* __restrict__ dinv, int2* __restrict__ csr, int E) {
    int e = blockIdx.x * 256 + threadIdx.x;
    if (e >= E) return;
    int s = src[e], d = dst[e];
    int p = rowst[d] + atomicAdd(&cursor[d], 1);
    csr[p] = make_int2(s, __float_as_int(dinv[s] * dinv[d]));
}

// ---- degree counting sort: perm groups nodes of equal degree into tiles ----

__global__ void k_hist(const int* __restrict__ deg, int* __restrict__ hist, int N) {
    int i = blockIdx.x * 256 + threadIdx.x;
    if (i < N) atomicAdd(&hist[min(deg[i], 63)], 1);
}

__global__ __launch_bounds__(64) void k_hscan(const int* __restrict__ hist,
                                              int* __restrict__ hbase) {
    __shared__ int s[64];
    int t = threadIdx.x;
    s[t] = hist[t];
    __syncthreads();
    if (t == 0) {
        int run = 0;
        for (int i = 0; i < 64; ++i) { int v = s[i]; s[i] = run; run += v; }
    }
    __syncthreads();
    hbase[t] = s[t];
}

__global__ void k_scatter(const int* __restrict__ deg, const int* __restrict__ hbase,
                          int* __restrict__ hcur, int* __restrict__ perm, int N) {
    int i = blockIdx.x * 256 + threadIdx.x;
    if (i < N) {
        int b = min(deg[i], 63);
        int p = hbase[b] + atomicAdd(&hcur[b], 1);
        perm[p] = i;
    }
}

// ---------------- weight fragment packing ----------------

// Ws[9][128][128] fp32 -> per-lane MFMA B fragments, hi/lo bf16:
// wf[((l*4+ks)*8+nt)*64 + lane][8 words]: words 0-3 = hi frag, 4-7 = lo frag
__global__ __launch_bounds__(64) void k_wconv(const float* __restrict__ Ws,
                                              unsigned int* __restrict__ wf) {
    int b = blockIdx.x;              // l*32 + ks*8 + nt
    int l = b >> 5, ks = (b >> 3) & 3, nt = b & 7;
    int lane = threadIdx.x;
    int g = lane >> 4, c = (lane & 15) + nt * 16;
    const float* W = Ws + (size_t)l * D * D;
    unsigned int hw[4], lw[4];
#pragma unroll
    for (int w = 0; w < 4; ++w) {
        unsigned short hs[2], ls[2];
#pragma unroll
        for (int j = 0; j < 2; ++j) {
            int e = 2 * w + j;
            int k = ks * 32 + 4 * g + (e & 3) + 16 * (e >> 2);
            f2hl(W[k * D + c], hs[j], ls[j]);
        }
        hw[w] = (unsigned int)hs[0] | ((unsigned int)hs[1] << 16);
        lw[w] = (unsigned int)ls[0] | ((unsigned int)ls[1] << 16);
    }
    unsigned int* dstp = wf + ((size_t)((l * 4 + ks) * 8 + nt) * 64 + lane) * 8;
    *(uint4*)dstp = make_uint4(hw[0], hw[1], hw[2], hw[3]);
    *(uint4*)(dstp + 4) = make_uint4(lw[0], lw[1], lw[2], lw[3]);
}

// Wo[128,16] fp32 -> wof[(ks*64 + lane)*8]: hi frag words 0-3, lo words 4-7
__global__ __launch_bounds__(64) void k_woconv(const float* __restrict__ Wo,
                                               unsigned int* __restrict__ wof) {
    int ks = blockIdx.x;
    int lane = threadIdx.x;
    int g = lane >> 4, c = lane & 15;
    unsigned int hw[4], lw[4];
#pragma unroll
    for (int w = 0; w < 4; ++w) {
        unsigned short hs[2], ls[2];
#pragma unroll
        for (int j = 0; j < 2; ++j) {
            int e = 2 * w + j;
            int k = ks * 32 + 4 * g + (e & 3) + 16 * (e >> 2);
            f2hl(Wo[k * 16 + c], hs[j], ls[j]);
        }
        hw[w] = (unsigned int)hs[0] | ((unsigned int)hs[1] << 16);
        lw[w] = (unsigned int)ls[0] | ((unsigned int)ls[1] << 16);
    }
    unsigned int* dstp = wof + ((size_t)(ks * 64 + lane)) * 8;
    *(uint4*)dstp = make_uint4(hw[0], hw[1], hw[2], hw[3]);
    *(uint4*)(dstp + 4) = make_uint4(lw[0], lw[1], lw[2], lw[3]);
}

// ---------------- fused layer: hout = act( (A_norm . hin) @ W + b ) ----------------
// Tile t covers permuted rows perm[nb..nb+ROWS) -- degree-sorted, so all nodes in a
// block have (nearly) equal degree: the phase-1 -> phase-2 barrier waits ~0.
// Phase 1: THREADS/32 groups of 32 lanes gather/aggregate nodes into LDS (fp32),
//          MFMA-permuted + XOR-bank-swizzled, sequential unroll-4 walk.
// Phase 2: waves cover ROWS x (NTT*16) outputs via split-bf16 MFMA, bias(+ReLU);
//          row i of the tile stores to hout[perm[nb+i]].

template <int THREADS, int ROWS, int NTT, int RELU, int OSTRIDE>
__global__ __launch_bounds__(THREADS, 8) void k_fused(const float* __restrict__ hin,
                                                      const int2* __restrict__ csr,
                                                      const int* __restrict__ rowst,
                                                      const int* __restrict__ deg,
                                                      const float* __restrict__ dinv,
                                                      const int* __restrict__ perm,
                                                      const unsigned int* __restrict__ wf,
                                                      const float* __restrict__ bias,
                                                      float* __restrict__ hout, int N) {
    __shared__ float sT[ROWS * 128];
    const int nb = blockIdx.x * ROWS;
    constexpr int NGRP = THREADS / 32;

    // ---- phase 1: aggregate ROWS rows into LDS ----
    {
        const int gp = threadIdx.x >> 5;
        const int l32 = threadIdx.x & 31;
        const int c = l32 << 2;
        const int p0 = permc(c);
        for (int s = gp; s < ROWS; s += NGRP) {
            int srow = nb + s;
            if (srow >= N) continue;
            int node = perm[srow];
            float di = dinv[node];
            float s2 = di * di;
            float4 t0 = *(const float4*)&hin[(size_t)node * D + c];
            float4 acc;
            acc.x = s2 * t0.x; acc.y = s2 * t0.y;
            acc.z = s2 * t0.z; acc.w = s2 * t0.w;

            int s0 = rowst[node];
            int cnt = deg[node];
            int j = 0;
            for (; j + 4 <= cnt; j += 4) {
                int2 e0 = csr[s0 + j + 0];
                int2 e1 = csr[s0 + j + 1];
                int2 e2 = csr[s0 + j + 2];
                int2 e3 = csr[s0 + j + 3];
                float4 r0 = *(const float4*)&hin[(size_t)e0.x * D + c];
                float4 r1 = *(const float4*)&hin[(size_t)e1.x * D + c];
                float4 r2 = *(const float4*)&hin[(size_t)e2.x * D + c];
                float4 r3 = *(const float4*)&hin[(size_t)e3.x * D + c];
                float w0 = __int_as_float(e0.y), w1 = __int_as_float(e1.y);
                float w2 = __int_as_float(e2.y), w3 = __int_as_float(e3.y);
                acc.x = fmaf(w0, r0.x, acc.x); acc.y = fmaf(w0, r0.y, acc.y);
                acc.z = fmaf(w0, r0.z, acc.z); acc.w = fmaf(w0, r0.w, acc.w);
                acc.x = fmaf(w1, r1.x, acc.x); acc.y = fmaf(w1, r1.y, acc.y);
                acc.z = fmaf(w1, r1.z, acc.z); acc.w = fmaf(w1, r1.w, acc.w);
                acc.x = fmaf(w2, r2.x, acc.x); acc.y = fmaf(w2, r2.y, acc.y);
                acc.z = fmaf(w2, r2.z, acc.z); acc.w = fmaf(w2, r2.w, acc.w);
                acc.x = fmaf(w3, r3.x, acc.x); acc.y = fmaf(w3, r3.y, acc.y);
                acc.z = fmaf(w3, r3.z, acc.z); acc.w = fmaf(w3, r3.w, acc.w);
            }
            for (; j < cnt; ++j) {
                int2 e = csr[s0 + j];
                float4 r = *(const float4*)&hin[(size_t)e.x * D + c];
                float w = __int_as_float(e.y);
                acc.x = fmaf(w, r.x, acc.x); acc.y = fmaf(w, r.y, acc.y);
                acc.z = fmaf(w, r.z, acc.z); acc.w = fmaf(w, r.w, acc.w);
            }
            // MFMA-permuted + bank-swizzled LDS store
            int idx = s * 128 + (p0 ^ ((s & 7) << 2));
            *(float4*)&sT[idx] = acc;
        }
    }
    __syncthreads();

    // ---- phase 2: split-bf16 MFMA ----
    constexpr int WAVES = THREADS / 64;
    constexpr int WR = (ROWS / 16 < WAVES) ? ROWS / 16 : WAVES;  // row tiles
    constexpr int CG = WAVES / WR;        // col groups (waves per row tile)
    constexpr int NTW = NTT / CG;         // col tiles per wave
    const int w = threadIdx.x >> 6;
    const int lane = threadIdx.x & 63;
    const int q = lane & 15, g = lane >> 4;
    const int rtile = w % WR;
    const int cg = w / WR;
    const int rloc = rtile * 16 + q;
    const int sw = (q & 7) << 2;

    v4f acc[NTW];
#pragma unroll
    for (int nt = 0; nt < NTW; ++nt) acc[nt] = (v4f)0.f;

    const float* rp = &sT[rloc * 128];

#pragma unroll
    for (int ks = 0; ks < 4; ++ks) {
        int o = ks * 32 + g * 8;
        float4 fa = *(const float4*)&rp[o ^ sw];
        float4 fb = *(const float4*)&rp[(o + 4) ^ sw];
        v8s ah, al;
        {
            unsigned short h_, l_;
            f2hl(fa.x, h_, l_); ah[0] = (short)h_; al[0] = (short)l_;
            f2hl(fa.y, h_, l_); ah[1] = (short)h_; al[1] = (short)l_;
            f2hl(fa.z, h_, l_); ah[2] = (short)h_; al[2] = (short)l_;
            f2hl(fa.w, h_, l_); ah[3] = (short)h_; al[3] = (short)l_;
            f2hl(fb.x, h_, l_); ah[4] = (short)h_; al[4] = (short)l_;
            f2hl(fb.y, h_, l_); ah[5] = (short)h_; al[5] = (short)l_;
            f2hl(fb.z, h_, l_); ah[6] = (short)h_; al[6] = (short)l_;
            f2hl(fb.w, h_, l_); ah[7] = (short)h_; al[7] = (short)l_;
        }
        const unsigned int* wk = wf + ((size_t)(ks * NTT + cg * NTW) * 64 + lane) * 8;
#pragma unroll
        for (int nt = 0; nt < NTW; ++nt) {
            v8s wh = *(const v8s*)(wk + nt * 512);
            v8s wl = *(const v8s*)(wk + nt * 512 + 4);
            acc[nt] = __builtin_amdgcn_mfma_f32_16x16x32_bf16(ah, wh, acc[nt], 0, 0, 0);
            acc[nt] = __builtin_amdgcn_mfma_f32_16x16x32_bf16(al, wh, acc[nt], 0, 0, 0);
            acc[nt] = __builtin_amdgcn_mfma_f32_16x16x32_bf16(ah, wl, acc[nt], 0, 0, 0);
        }
    }

    // ---- epilogue: bias (+ReLU), store to perm'd rows. C/D: col=q, row=4g+i ----
    const int growb = nb + rtile * 16 + 4 * g;
#pragma unroll
    for (int nt = 0; nt < NTW; ++nt) {
        int col = (cg * NTW + nt) * 16 + q;
        float bv = bias[col];
#pragma unroll
        for (int i = 0; i < 4; ++i) {
            int grow = growb + i;
            if (grow < N) {
                int prow = perm[grow];
                float v = acc[nt][i] + bv;
                if (RELU) v = fmaxf(v, 0.f);
                hout[(size_t)prow * OSTRIDE + col] = v;
            }
        }
    }
}

// ---------------- launch ----------------

extern "C" void kernel_launch(void* const* d_in, const int* in_sizes, int n_in,
                              void* d_out, int out_size, void* d_ws, size_t ws_size,
                              hipStream_t stream) {
    const float* x  = (const float*)d_in[0];
    const int*   ei = (const int*)d_in[1];
    const float* Ws = (const float*)d_in[2];
    const float* bs = (const float*)d_in[3];
    const float* Wo = (const float*)d_in[4];
    const float* bo = (const float*)d_in[5];
    float* out = (float*)d_out;

    const int N = in_sizes[0] / D;     // 100000
    const int E = in_sizes[1] / 2;     // 600000
    const int* src = ei;
    const int* dst = ei + E;

    // workspace layout (~110 MB)
    float* H0     = (float*)d_ws;                     // N*128 fp32 ping
    float* H1     = H0 + (size_t)N * D;               // N*128 fp32 pong
    int*   deg    = (int*)(H1 + (size_t)N * D);
    int*   cursor = deg + N;
    int*   rowst  = cursor + N;
    float* dinv   = (float*)(rowst + N);
    int*   bsums  = (int*)(dinv + N);
    int2*  csr    = (int2*)(bsums + 1024);
    unsigned int* wfrag  = (unsigned int*)(csr + E);  // 9 * 16384 uints (576 KB)
    unsigned int* wofrag = wfrag + 9 * 16384;         // 2048 uints (8 KB)
    int*   hist   = (int*)(wofrag + 2048);            // 64
    int*   hbase  = hist + 64;                        // 64
    int*   hcur   = hbase + 64;                       // 64
    int*   perm   = hcur + 64;                        // N

    const int NB = (N + 1023) / 1024;

    hipMemsetAsync(deg, 0, (size_t)2 * N * sizeof(int), stream);  // deg + cursor
    hipMemsetAsync(hist, 0, 192 * sizeof(int), stream);           // hist+hbase+hcur
    k_count<<<(E + 255) / 256, 256, 0, stream>>>(dst, deg, E);
    k_blocksum<<<NB, 256, 0, stream>>>(deg, bsums, N);
    k_scanbsums<<<1, 256, 0, stream>>>(bsums, NB);
    k_scan2<<<NB, 256, 0, stream>>>(deg, bsums, rowst, dinv, N);
    k_fill<<<(E + 255) / 256, 256, 0, stream>>>(src, dst, rowst, cursor, dinv, csr, E);

    // degree counting sort
    k_hist<<<(N + 255) / 256, 256, 0, stream>>>(deg, hist, N);
    k_hscan<<<1, 64, 0, stream>>>(hist, hbase);
    k_scatter<<<(N + 255) / 256, 256, 0, stream>>>(deg, hbase, hcur, perm, N);

    k_wconv<<<288, 64, 0, stream>>>(Ws, wfrag);
    k_woconv<<<4, 64, 0, stream>>>(Wo, wofrag);

    const float* hin = x;
    float* hout = H0;
    const int gblk16 = (N + 15) / 16;
    for (int l = 0; l < 9; ++l) {
        k_fused<128, 16, 8, 1, 128><<<gblk16, 128, 0, stream>>>(hin, csr, rowst, deg,
                                                                dinv, perm,
                                                                wfrag + (size_t)l * 16384,
                                                                bs + (size_t)l * D,
                                                                hout, N);
        hin = hout;
        hout = (hout == H0) ? H1 : H0;
    }
    const int gblk64 = (N + 63) / 64;
    k_fused<256, 64, 1, 0, 16><<<gblk64, 256, 0, stream>>>(hin, csr, rowst, deg, dinv,
                                                           perm, wofrag, bo, out, N);
}

// Round 8
// 944.464 us; speedup vs baseline: 1.7461x; 1.7461x over previous
//
#include <hip/hip_runtime.h>

#define D 128

typedef short v8s __attribute__((ext_vector_type(8)));
typedef float v4f __attribute__((ext_vector_type(4)));

// fp32 -> bf16 hi/lo split: f ~= hi + lo, |err| ~ 2^-17 * |f|
__device__ __forceinline__ void f2hl(float f, unsigned short& h, unsigned short& l) {
    unsigned int u = __float_as_uint(f);
    unsigned int hu = u & 0xffff0000u;
    float lf = f - __uint_as_float(hu);          // exact
    h = (unsigned short)(hu >> 16);
    l = (unsigned short)((__float_as_uint(lf) + 0x8000u) >> 16);  // round
}

// permuted column position for a 4-aligned k chunk (MFMA A-frag contiguous layout)
// k = 4g + (e&3) + 16*(e>>2)  <->  p = 8g + e   (within each 32-wide k block)
__device__ __forceinline__ int permc(int c) {
    return (c & ~31) + ((c & 12) << 1) + ((c & 16) >> 2);
}

// ---------------- preprocessing ----------------

__global__ void k_count(const int* __restrict__ dst, int* __restrict__ deg, int E) {
    int e = blockIdx.x * 256 + threadIdx.x;
    if (e < E) atomicAdd(&deg[dst[e]], 1);
}

__global__ __launch_bounds__(256) void k_blocksum(const int* __restrict__ deg,
                                                  int* __restrict__ bsums, int N) {
    __shared__ int s[256];
    int base = blockIdx.x * 1024 + threadIdx.x * 4;
    int v = 0;
#pragma unroll
    for (int j = 0; j < 4; ++j) { int i = base + j; if (i < N) v += deg[i]; }
    s[threadIdx.x] = v;
    __syncthreads();
    for (int off = 128; off > 0; off >>= 1) {
        if (threadIdx.x < off) s[threadIdx.x] += s[threadIdx.x + off];
        __syncthreads();
    }
    if (threadIdx.x == 0) bsums[blockIdx.x] = s[0];
}

__global__ __launch_bounds__(256) void k_scanbsums(int* __restrict__ bsums, int NB) {
    __shared__ int s[256];
    __shared__ int carry;
    int t = threadIdx.x;
    if (t == 0) carry = 0;
    __syncthreads();
    for (int base = 0; base < NB; base += 256) {
        int i = base + t;
        int v = (i < NB) ? bsums[i] : 0;
        s[t] = v;
        __syncthreads();
        for (int off = 1; off < 256; off <<= 1) {
            int x = (t >= off) ? s[t - off] : 0;
            __syncthreads();
            s[t] += x;
            __syncthreads();
        }
        if (i < NB) bsums[i] = carry + s[t] - v;   // exclusive
        __syncthreads();
        if (t == 0) carry += s[255];
        __syncthreads();
    }
}

__global__ __launch_bounds__(256) void k_scan2(const int* __restrict__ deg,
                                               const int* __restrict__ bsums,
                                               int* __restrict__ rowst,
                                               float* __restrict__ dinv, int N) {
    __shared__ int s[256];
    int t = threadIdx.x;
    int base = blockIdx.x * 1024 + t * 4;
    int v[4];
#pragma unroll
    for (int j = 0; j < 4; ++j) { int i = base + j; v[j] = (i < N) ? deg[i] : 0; }
    int tsum = v[0] + v[1] + v[2] + v[3];
    s[t] = tsum;
    __syncthreads();
    for (int off = 1; off < 256; off <<= 1) {
        int x = (t >= off) ? s[t - off] : 0;
        __syncthreads();
        s[t] += x;
        __syncthreads();
    }
    int run = s[t] - tsum + bsums[blockIdx.x];
#pragma unroll
    for (int j = 0; j < 4; ++j) {
        int i = base + j;
        if (i < N) {
            rowst[i] = run;
            dinv[i] = rsqrtf((float)(v[j] + 1));   // +1 for self-loop
        }
        run += v[j];
    }
}

__global__ void k_fill(const int* __restrict__ src, const int* __restrict__ dst,
                       const int* __restrict__ rowst, int* __restrict__ cursor,
                       const float* __restrict__ dinv, int2* __restrict__ csr, int E) {
    int e = blockIdx.x * 256 + threadIdx.x;
    if (e >= E) return;
    int s = src[e], d = dst[e];
    int p = rowst[d] + atomicAdd(&cursor[d], 1);
    csr[p] = make_int2(s, __float_as_int(dinv[s] * dinv[d]));
}

// ---- blocked degree counting sort (no hot global atomics) ----
// perm groups nodes of (nearly) equal degree into consecutive tiles.

__global__ __launch_bounds__(256) void k_bhist(const int* __restrict__ deg,
                                               int* __restrict__ bhist, int N, int NBLK) {
    __shared__ int h[64];
    int t = threadIdx.x;
    if (t < 64) h[t] = 0;
    __syncthreads();
    int i = blockIdx.x * 256 + t;
    if (i < N) atomicAdd(&h[min(deg[i], 63)], 1);
    __syncthreads();
    if (t < 64) bhist[t * NBLK + blockIdx.x] = h[t];
}

__global__ __launch_bounds__(256) void k_bscan(int* __restrict__ a, int L) {
    __shared__ int s[256];
    int t = threadIdx.x;
    int chunk = (L + 255) / 256;
    int b0 = t * chunk;
    int b1 = min(b0 + chunk, L);
    int sum = 0;
    for (int i = b0; i < b1; ++i) sum += a[i];
    s[t] = sum;
    __syncthreads();
    for (int off = 1; off < 256; off <<= 1) {
        int x = (t >= off) ? s[t - off] : 0;
        __syncthreads();
        s[t] += x;
        __syncthreads();
    }
    int run = s[t] - sum;    // exclusive prefix of this thread's chunk
    for (int i = b0; i < b1; ++i) { int v = a[i]; a[i] = run; run += v; }
}

__global__ __launch_bounds__(256) void k_bscatter(const int* __restrict__ deg,
                                                  const int* __restrict__ bbase,
                                                  int* __restrict__ perm, int N, int NBLK) {
    __shared__ int h[64];
    int t = threadIdx.x;
    if (t < 64) h[t] = 0;
    __syncthreads();
    int i = blockIdx.x * 256 + t;
    if (i < N) {
        int b = min(deg[i], 63);
        int r = atomicAdd(&h[b], 1);            // LDS: local rank within block
        perm[bbase[b * NBLK + blockIdx.x] + r] = i;
    }
}

// ---------------- weight fragment packing ----------------

// Ws[9][128][128] fp32 -> per-lane MFMA B fragments, hi/lo bf16:
// wf[((l*4+ks)*8+nt)*64 + lane][8 words]: words 0-3 = hi frag, 4-7 = lo frag
__global__ __launch_bounds__(64) void k_wconv(const float* __restrict__ Ws,
                                              unsigned int* __restrict__ wf) {
    int b = blockIdx.x;              // l*32 + ks*8 + nt
    int l = b >> 5, ks = (b >> 3) & 3, nt = b & 7;
    int lane = threadIdx.x;
    int g = lane >> 4, c = (lane & 15) + nt * 16;
    const float* W = Ws + (size_t)l * D * D;
    unsigned int hw[4], lw[4];
#pragma unroll
    for (int w = 0; w < 4; ++w) {
        unsigned short hs[2], ls[2];
#pragma unroll
        for (int j = 0; j < 2; ++j) {
            int e = 2 * w + j;
            int k = ks * 32 + 4 * g + (e & 3) + 16 * (e >> 2);
            f2hl(W[k * D + c], hs[j], ls[j]);
        }
        hw[w] = (unsigned int)hs[0] | ((unsigned int)hs[1] << 16);
        lw[w] = (unsigned int)ls[0] | ((unsigned int)ls[1] << 16);
    }
    unsigned int* dstp = wf + ((size_t)((l * 4 + ks) * 8 + nt) * 64 + lane) * 8;
    *(uint4*)dstp = make_uint4(hw[0], hw[1], hw[2], hw[3]);
    *(uint4*)(dstp + 4) = make_uint4(lw[0], lw[1], lw[2], lw[3]);
}

// Wo[128,16] fp32 -> wof[(ks*64 + lane)*8]: hi frag words 0-3, lo words 4-7
__global__ __launch_bounds__(64) void k_woconv(const float* __restrict__ Wo,
                                               unsigned int* __restrict__ wof) {
    int ks = blockIdx.x;
    int lane = threadIdx.x;
    int g = lane >> 4, c = lane & 15;
    unsigned int hw[4], lw[4];
#pragma unroll
    for (int w = 0; w < 4; ++w) {
        unsigned short hs[2], ls[2];
#pragma unroll
        for (int j = 0; j < 2; ++j) {
            int e = 2 * w + j;
            int k = ks * 32 + 4 * g + (e & 3) + 16 * (e >> 2);
            f2hl(Wo[k * 16 + c], hs[j], ls[j]);
        }
        hw[w] = (unsigned int)hs[0] | ((unsigned int)hs[1] << 16);
        lw[w] = (unsigned int)ls[0] | ((unsigned int)ls[1] << 16);
    }
    unsigned int* dstp = wof + ((size_t)(ks * 64 + lane)) * 8;
    *(uint4*)dstp = make_uint4(hw[0], hw[1], hw[2], hw[3]);
    *(uint4*)(dstp + 4) = make_uint4(lw[0], lw[1], lw[2], lw[3]);
}

// ---------------- fused layer: hout = act( (A_norm . hin) @ W + b ) ----------------
// Tile t covers permuted rows perm[nb..nb+ROWS) -- degree-sorted, so all nodes in a
// block have (nearly) equal degree: the phase-1 -> phase-2 barrier waits ~0.
// Phase 1: THREADS/32 groups of 32 lanes gather/aggregate nodes into LDS (fp32),
//          MFMA-permuted + XOR-bank-swizzled, sequential unroll-4 walk.
// Phase 2: waves cover ROWS x (NTT*16) outputs via split-bf16 MFMA, bias(+ReLU);
//          row i of the tile stores to hout[perm[nb+i]].

template <int THREADS, int ROWS, int NTT, int RELU, int OSTRIDE>
__global__ __launch_bounds__(THREADS, 8) void k_fused(const float* __restrict__ hin,
                                                      const int2* __restrict__ csr,
                                                      const int* __restrict__ rowst,
                                                      const int* __restrict__ deg,
                                                      const float* __restrict__ dinv,
                                                      const int* __restrict__ perm,
                                                      const unsigned int* __restrict__ wf,
                                                      const float* __restrict__ bias,
                                                      float* __restrict__ hout, int N) {
    __shared__ float sT[ROWS * 128];
    const int nb = blockIdx.x * ROWS;
    constexpr int NGRP = THREADS / 32;

    // ---- phase 1: aggregate ROWS rows into LDS ----
    {
        const int gp = threadIdx.x >> 5;
        const int l32 = threadIdx.x & 31;
        const int c = l32 << 2;
        const int p0 = permc(c);
        for (int s = gp; s < ROWS; s += NGRP) {
            int srow = nb + s;
            if (srow >= N) continue;
            int node = perm[srow];
            float di = dinv[node];
            float s2 = di * di;
            float4 t0 = *(const float4*)&hin[(size_t)node * D + c];
            float4 acc;
            acc.x = s2 * t0.x; acc.y = s2 * t0.y;
            acc.z = s2 * t0.z; acc.w = s2 * t0.w;

            int s0 = rowst[node];
            int cnt = deg[node];
            int j = 0;
            for (; j + 4 <= cnt; j += 4) {
                int2 e0 = csr[s0 + j + 0];
                int2 e1 = csr[s0 + j + 1];
                int2 e2 = csr[s0 + j + 2];
                int2 e3 = csr[s0 + j + 3];
                float4 r0 = *(const float4*)&hin[(size_t)e0.x * D + c];
                float4 r1 = *(const float4*)&hin[(size_t)e1.x * D + c];
                float4 r2 = *(const float4*)&hin[(size_t)e2.x * D + c];
                float4 r3 = *(const float4*)&hin[(size_t)e3.x * D + c];
                float w0 = __int_as_float(e0.y), w1 = __int_as_float(e1.y);
                float w2 = __int_as_float(e2.y), w3 = __int_as_float(e3.y);
                acc.x = fmaf(w0, r0.x, acc.x); acc.y = fmaf(w0, r0.y, acc.y);
                acc.z = fmaf(w0, r0.z, acc.z); acc.w = fmaf(w0, r0.w, acc.w);
                acc.x = fmaf(w1, r1.x, acc.x); acc.y = fmaf(w1, r1.y, acc.y);
                acc.z = fmaf(w1, r1.z, acc.z); acc.w = fmaf(w1, r1.w, acc.w);
                acc.x = fmaf(w2, r2.x, acc.x); acc.y = fmaf(w2, r2.y, acc.y);
                acc.z = fmaf(w2, r2.z, acc.z); acc.w = fmaf(w2, r2.w, acc.w);
                acc.x = fmaf(w3, r3.x, acc.x); acc.y = fmaf(w3, r3.y, acc.y);
                acc.z = fmaf(w3, r3.z, acc.z); acc.w = fmaf(w3, r3.w, acc.w);
            }
            for (; j < cnt; ++j) {
                int2 e = csr[s0 + j];
                float4 r = *(const float4*)&hin[(size_t)e.x * D + c];
                float w = __int_as_float(e.y);
                acc.x = fmaf(w, r.x, acc.x); acc.y = fmaf(w, r.y, acc.y);
                acc.z = fmaf(w, r.z, acc.z); acc.w = fmaf(w, r.w, acc.w);
            }
            // MFMA-permuted + bank-swizzled LDS store
            int idx = s * 128 + (p0 ^ ((s & 7) << 2));
            *(float4*)&sT[idx] = acc;
        }
    }
    __syncthreads();

    // ---- phase 2: split-bf16 MFMA ----
    constexpr int WAVES = THREADS / 64;
    constexpr int WR = (ROWS / 16 < WAVES) ? ROWS / 16 : WAVES;  // row tiles
    constexpr int CG = WAVES / WR;        // col groups (waves per row tile)
    constexpr int NTW = NTT / CG;         // col tiles per wave
    const int w = threadIdx.x >> 6;
    const int lane = threadIdx.x & 63;
    const int q = lane & 15, g = lane >> 4;
    const int rtile = w % WR;
    const int cg = w / WR;
    const int rloc = rtile * 16 + q;
    const int sw = (q & 7) << 2;

    v4f acc[NTW];
#pragma unroll
    for (int nt = 0; nt < NTW; ++nt) acc[nt] = (v4f)0.f;

    const float* rp = &sT[rloc * 128];

#pragma unroll
    for (int ks = 0; ks < 4; ++ks) {
        int o = ks * 32 + g * 8;
        float4 fa = *(const float4*)&rp[o ^ sw];
        float4 fb = *(const float4*)&rp[(o + 4) ^ sw];
        v8s ah, al;
        {
            unsigned short h_, l_;
            f2hl(fa.x, h_, l_); ah[0] = (short)h_; al[0] = (short)l_;
            f2hl(fa.y, h_, l_); ah[1] = (short)h_; al[1] = (short)l_;
            f2hl(fa.z, h_, l_); ah[2] = (short)h_; al[2] = (short)l_;
            f2hl(fa.w, h_, l_); ah[3] = (short)h_; al[3] = (short)l_;
            f2hl(fb.x, h_, l_); ah[4] = (short)h_; al[4] = (short)l_;
            f2hl(fb.y, h_, l_); ah[5] = (short)h_; al[5] = (short)l_;
            f2hl(fb.z, h_, l_); ah[6] = (short)h_; al[6] = (short)l_;
            f2hl(fb.w, h_, l_); ah[7] = (short)h_; al[7] = (short)l_;
        }
        const unsigned int* wk = wf + ((size_t)(ks * NTT + cg * NTW) * 64 + lane) * 8;
#pragma unroll
        for (int nt = 0; nt < NTW; ++nt) {
            v8s wh = *(const v8s*)(wk + nt * 512);
            v8s wl = *(const v8s*)(wk + nt * 512 + 4);
            acc[nt] = __builtin_amdgcn_mfma_f32_16x16x32_bf16(ah, wh, acc[nt], 0, 0, 0);
            acc[nt] = __builtin_amdgcn_mfma_f32_16x16x32_bf16(al, wh, acc[nt], 0, 0, 0);
            acc[nt] = __builtin_amdgcn_mfma_f32_16x16x32_bf16(ah, wl, acc[nt], 0, 0, 0);
        }
    }

    // ---- epilogue: bias (+ReLU), store to perm'd rows. C/D: col=q, row=4g+i ----
    const int growb = nb + rtile * 16 + 4 * g;
#pragma unroll
    for (int nt = 0; nt < NTW; ++nt) {
        int col = (cg * NTW + nt) * 16 + q;
        float bv = bias[col];
#pragma unroll
        for (int i = 0; i < 4; ++i) {
            int grow = growb + i;
            if (grow < N) {
                int prow = perm[grow];
                float v = acc[nt][i] + bv;
                if (RELU) v = fmaxf(v, 0.f);
                hout[(size_t)prow * OSTRIDE + col] = v;
            }
        }
    }
}

// ---------------- launch ----------------

extern "C" void kernel_launch(void* const* d_in, const int* in_sizes, int n_in,
                              void* d_out, int out_size, void* d_ws, size_t ws_size,
                              hipStream_t stream) {
    const float* x  = (const float*)d_in[0];
    const int*   ei = (const int*)d_in[1];
    const float* Ws = (const float*)d_in[2];
    const float* bs = (const float*)d_in[3];
    const float* Wo = (const float*)d_in[4];
    const float* bo = (const float*)d_in[5];
    float* out = (float*)d_out;

    const int N = in_sizes[0] / D;     // 100000
    const int E = in_sizes[1] / 2;     // 600000
    const int* src = ei;
    const int* dst = ei + E;

    // workspace layout (~111 MB)
    float* H0     = (float*)d_ws;                     // N*128 fp32 ping
    float* H1     = H0 + (size_t)N * D;               // N*128 fp32 pong
    int*   deg    = (int*)(H1 + (size_t)N * D);
    int*   cursor = deg + N;
    int*   rowst  = cursor + N;
    float* dinv   = (float*)(rowst + N);
    int*   bsums  = (int*)(dinv + N);
    int2*  csr    = (int2*)(bsums + 1024);
    unsigned int* wfrag  = (unsigned int*)(csr + E);  // 9 * 16384 uints (576 KB)
    unsigned int* wofrag = wfrag + 9 * 16384;         // 2048 uints (8 KB)
    const int NBLK = (N + 255) / 256;                 // histogram blocks
    int*   bhist  = (int*)(wofrag + 2048);            // 64 * NBLK
    int*   perm   = bhist + 64 * NBLK;                // N

    const int NB = (N + 1023) / 1024;

    hipMemsetAsync(deg, 0, (size_t)2 * N * sizeof(int), stream);  // deg + cursor
    k_count<<<(E + 255) / 256, 256, 0, stream>>>(dst, deg, E);
    k_blocksum<<<NB, 256, 0, stream>>>(deg, bsums, N);
    k_scanbsums<<<1, 256, 0, stream>>>(bsums, NB);
    k_scan2<<<NB, 256, 0, stream>>>(deg, bsums, rowst, dinv, N);
    k_fill<<<(E + 255) / 256, 256, 0, stream>>>(src, dst, rowst, cursor, dinv, csr, E);

    // blocked degree counting sort (LDS histograms, no hot global atomics)
    k_bhist<<<NBLK, 256, 0, stream>>>(deg, bhist, N, NBLK);
    k_bscan<<<1, 256, 0, stream>>>(bhist, 64 * NBLK);
    k_bscatter<<<NBLK, 256, 0, stream>>>(deg, bhist, perm, N, NBLK);

    k_wconv<<<288, 64, 0, stream>>>(Ws, wfrag);
    k_woconv<<<4, 64, 0, stream>>>(Wo, wofrag);

    const float* hin = x;
    float* hout = H0;
    const int gblk16 = (N + 15) / 16;
    for (int l = 0; l < 9; ++l) {
        k_fused<128, 16, 8, 1, 128><<<gblk16, 128, 0, stream>>>(hin, csr, rowst, deg,
                                                                dinv, perm,
                                                                wfrag + (size_t)l * 16384,
                                                                bs + (size_t)l * D,
                                                                hout, N);
        hin = hout;
        hout = (hout == H0) ? H1 : H0;
    }
    const int gblk64 = (N + 63) / 64;
    k_fused<256, 64, 1, 0, 16><<<gblk64, 256, 0, stream>>>(hin, csr, rowst, deg, dinv,
                                                           perm, wofrag, bo, out, N);
}

// Round 9
// 863.259 us; speedup vs baseline: 1.9104x; 1.0941x over previous
//
#include <hip/hip_runtime.h>

#define D 128

typedef short v8s __attribute__((ext_vector_type(8)));
typedef float v4f __attribute__((ext_vector_type(4)));

// fp32 -> bf16 hi/lo split: f ~= hi + lo, |err| ~ 2^-17 * |f|
__device__ __forceinline__ void f2hl(float f, unsigned short& h, unsigned short& l) {
    unsigned int u = __float_as_uint(f);
    unsigned int hu = u & 0xffff0000u;
    float lf = f - __uint_as_float(hu);          // exact
    h = (unsigned short)(hu >> 16);
    l = (unsigned short)((__float_as_uint(lf) + 0x8000u) >> 16);  // round
}

// permuted column position for a 4-aligned k chunk (MFMA A-frag contiguous layout)
// k = 4g + (e&3) + 16*(e>>2)  <->  p = 8g + e   (within each 32-wide k block)
__device__ __forceinline__ int permc(int c) {
    return (c & ~31) + ((c & 12) << 1) + ((c & 16) >> 2);
}

// ---------------- preprocessing ----------------

__global__ void k_count(const int* __restrict__ dst, int* __restrict__ deg, int E) {
    int e = blockIdx.x * 256 + threadIdx.x;
    if (e < E) atomicAdd(&deg[dst[e]], 1);
}

__global__ __launch_bounds__(256) void k_blocksum(const int* __restrict__ deg,
                                                  int* __restrict__ bsums, int N) {
    __shared__ int s[256];
    int base = blockIdx.x * 1024 + threadIdx.x * 4;
    int v = 0;
#pragma unroll
    for (int j = 0; j < 4; ++j) { int i = base + j; if (i < N) v += deg[i]; }
    s[threadIdx.x] = v;
    __syncthreads();
    for (int off = 128; off > 0; off >>= 1) {
        if (threadIdx.x < off) s[threadIdx.x] += s[threadIdx.x + off];
        __syncthreads();
    }
    if (threadIdx.x == 0) bsums[blockIdx.x] = s[0];
}

__global__ __launch_bounds__(256) void k_scanbsums(int* __restrict__ bsums, int NB) {
    __shared__ int s[256];
    __shared__ int carry;
    int t = threadIdx.x;
    if (t == 0) carry = 0;
    __syncthreads();
    for (int base = 0; base < NB; base += 256) {
        int i = base + t;
        int v = (i < NB) ? bsums[i] : 0;
        s[t] = v;
        __syncthreads();
        for (int off = 1; off < 256; off <<= 1) {
            int x = (t >= off) ? s[t - off] : 0;
            __syncthreads();
            s[t] += x;
            __syncthreads();
        }
        if (i < NB) bsums[i] = carry + s[t] - v;   // exclusive
        __syncthreads();
        if (t == 0) carry += s[255];
        __syncthreads();
    }
}

__global__ __launch_bounds__(256) void k_scan2(const int* __restrict__ deg,
                                               const int* __restrict__ bsums,
                                               int* __restrict__ rowst,
                                               float* __restrict__ dinv, int N) {
    __shared__ int s[256];
    int t = threadIdx.x;
    int base = blockIdx.x * 1024 + t * 4;
    int v[4];
#pragma unroll
    for (int j = 0; j < 4; ++j) { int i = base + j; v[j] = (i < N) ? deg[i] : 0; }
    int tsum = v[0] + v[1] + v[2] + v[3];
    s[t] = tsum;
    __syncthreads();
    for (int off = 1; off < 256; off <<= 1) {
        int x = (t >= off) ? s[t - off] : 0;
        __syncthreads();
        s[t] += x;
        __syncthreads();
    }
    int run = s[t] - tsum + bsums[blockIdx.x];
#pragma unroll
    for (int j = 0; j < 4; ++j) {
        int i = base + j;
        if (i < N) {
            rowst[i] = run;
            dinv[i] = rsqrtf((float)(v[j] + 1));   // +1 for self-loop
        }
        run += v[j];
    }
}

__global__ void k_fill(const int* __restrict__ src, const int* __restrict__ dst,
                       const int* __restrict__ rowst, int* __restrict__ cursor,
                       const float* __restrict__ dinv, int2* __restrict__ csr, int E) {
    int e = blockIdx.x * 256 + threadIdx.x;
    if (e >= E) return;
    int s = src[e], d = dst[e];
    int p = rowst[d] + atomicAdd(&cursor[d], 1);
    csr[p] = make_int2(s, __float_as_int(dinv[s] * dinv[d]));
}

// ---------------- weight fragment packing ----------------

// Ws[9][128][128] fp32 -> per-lane MFMA B fragments, hi/lo bf16:
// wf[((l*4+ks)*8+nt)*64 + lane][8 words]: words 0-3 = hi frag, 4-7 = lo frag
__global__ __launch_bounds__(64) void k_wconv(const float* __restrict__ Ws,
                                              unsigned int* __restrict__ wf) {
    int b = blockIdx.x;              // l*32 + ks*8 + nt
    int l = b >> 5, ks = (b >> 3) & 3, nt = b & 7;
    int lane = threadIdx.x;
    int g = lane >> 4, c = (lane & 15) + nt * 16;
    const float* W = Ws + (size_t)l * D * D;
    unsigned int hw[4], lw[4];
#pragma unroll
    for (int w = 0; w < 4; ++w) {
        unsigned short hs[2], ls[2];
#pragma unroll
        for (int j = 0; j < 2; ++j) {
            int e = 2 * w + j;
            int k = ks * 32 + 4 * g + (e & 3) + 16 * (e >> 2);
            f2hl(W[k * D + c], hs[j], ls[j]);
        }
        hw[w] = (unsigned int)hs[0] | ((unsigned int)hs[1] << 16);
        lw[w] = (unsigned int)ls[0] | ((unsigned int)ls[1] << 16);
    }
    unsigned int* dstp = wf + ((size_t)((l * 4 + ks) * 8 + nt) * 64 + lane) * 8;
    *(uint4*)dstp = make_uint4(hw[0], hw[1], hw[2], hw[3]);
    *(uint4*)(dstp + 4) = make_uint4(lw[0], lw[1], lw[2], lw[3]);
}

// ---------------- fused hidden layer: hout = relu( (A_norm . hin) @ W + b ) --------
// 16-node tile per 128-thread block. Phase 1: 4 groups of 32 lanes gather/aggregate
// 4 nodes each into LDS (fp32), MFMA-permuted + XOR-bank-swizzled, UNROLL-8 walk
// (8 independent csr + row loads in flight per group for max MLP).
// Phase 2: 2 waves x (16 rows x 4 col tiles) split-bf16 MFMA, bias+ReLU, store.

template <int THREADS, int ROWS, int NTT, int RELU, int OSTRIDE>
__global__ __launch_bounds__(THREADS, 6) void k_fused(const float* __restrict__ hin,
                                                      const int2* __restrict__ csr,
                                                      const int* __restrict__ rowst,
                                                      const int* __restrict__ deg,
                                                      const float* __restrict__ dinv,
                                                      const unsigned int* __restrict__ wf,
                                                      const float* __restrict__ bias,
                                                      float* __restrict__ hout, int N) {
    __shared__ float sT[ROWS * 128];
    const int nb = blockIdx.x * ROWS;
    constexpr int NGRP = THREADS / 32;

    // ---- phase 1: aggregate ROWS rows into LDS ----
    {
        const int gp = threadIdx.x >> 5;
        const int l32 = threadIdx.x & 31;
        const int c = l32 << 2;
        const int p0 = permc(c);
        for (int s = gp; s < ROWS; s += NGRP) {
            int node = nb + s;
            if (node >= N) continue;
            float di = dinv[node];
            float s2 = di * di;
            float4 t0 = *(const float4*)&hin[(size_t)node * D + c];
            float4 acc;
            acc.x = s2 * t0.x; acc.y = s2 * t0.y;
            acc.z = s2 * t0.z; acc.w = s2 * t0.w;

            int s0 = rowst[node];
            int cnt = deg[node];
            int j = 0;
            for (; j + 8 <= cnt; j += 8) {
                int2 e0 = csr[s0 + j + 0];
                int2 e1 = csr[s0 + j + 1];
                int2 e2 = csr[s0 + j + 2];
                int2 e3 = csr[s0 + j + 3];
                int2 e4 = csr[s0 + j + 4];
                int2 e5 = csr[s0 + j + 5];
                int2 e6 = csr[s0 + j + 6];
                int2 e7 = csr[s0 + j + 7];
                float4 r0 = *(const float4*)&hin[(size_t)e0.x * D + c];
                float4 r1 = *(const float4*)&hin[(size_t)e1.x * D + c];
                float4 r2 = *(const float4*)&hin[(size_t)e2.x * D + c];
                float4 r3 = *(const float4*)&hin[(size_t)e3.x * D + c];
                float4 r4 = *(const float4*)&hin[(size_t)e4.x * D + c];
                float4 r5 = *(const float4*)&hin[(size_t)e5.x * D + c];
                float4 r6 = *(const float4*)&hin[(size_t)e6.x * D + c];
                float4 r7 = *(const float4*)&hin[(size_t)e7.x * D + c];
                float w0 = __int_as_float(e0.y), w1 = __int_as_float(e1.y);
                float w2 = __int_as_float(e2.y), w3 = __int_as_float(e3.y);
                float w4 = __int_as_float(e4.y), w5 = __int_as_float(e5.y);
                float w6 = __int_as_float(e6.y), w7 = __int_as_float(e7.y);
                acc.x = fmaf(w0, r0.x, acc.x); acc.y = fmaf(w0, r0.y, acc.y);
                acc.z = fmaf(w0, r0.z, acc.z); acc.w = fmaf(w0, r0.w, acc.w);
                acc.x = fmaf(w1, r1.x, acc.x); acc.y = fmaf(w1, r1.y, acc.y);
                acc.z = fmaf(w1, r1.z, acc.z); acc.w = fmaf(w1, r1.w, acc.w);
                acc.x = fmaf(w2, r2.x, acc.x); acc.y = fmaf(w2, r2.y, acc.y);
                acc.z = fmaf(w2, r2.z, acc.z); acc.w = fmaf(w2, r2.w, acc.w);
                acc.x = fmaf(w3, r3.x, acc.x); acc.y = fmaf(w3, r3.y, acc.y);
                acc.z = fmaf(w3, r3.z, acc.z); acc.w = fmaf(w3, r3.w, acc.w);
                acc.x = fmaf(w4, r4.x, acc.x); acc.y = fmaf(w4, r4.y, acc.y);
                acc.z = fmaf(w4, r4.z, acc.z); acc.w = fmaf(w4, r4.w, acc.w);
                acc.x = fmaf(w5, r5.x, acc.x); acc.y = fmaf(w5, r5.y, acc.y);
                acc.z = fmaf(w5, r5.z, acc.z); acc.w = fmaf(w5, r5.w, acc.w);
                acc.x = fmaf(w6, r6.x, acc.x); acc.y = fmaf(w6, r6.y, acc.y);
                acc.z = fmaf(w6, r6.z, acc.z); acc.w = fmaf(w6, r6.w, acc.w);
                acc.x = fmaf(w7, r7.x, acc.x); acc.y = fmaf(w7, r7.y, acc.y);
                acc.z = fmaf(w7, r7.z, acc.z); acc.w = fmaf(w7, r7.w, acc.w);
            }
            for (; j + 4 <= cnt; j += 4) {
                int2 e0 = csr[s0 + j + 0];
                int2 e1 = csr[s0 + j + 1];
                int2 e2 = csr[s0 + j + 2];
                int2 e3 = csr[s0 + j + 3];
                float4 r0 = *(const float4*)&hin[(size_t)e0.x * D + c];
                float4 r1 = *(const float4*)&hin[(size_t)e1.x * D + c];
                float4 r2 = *(const float4*)&hin[(size_t)e2.x * D + c];
                float4 r3 = *(const float4*)&hin[(size_t)e3.x * D + c];
                float w0 = __int_as_float(e0.y), w1 = __int_as_float(e1.y);
                float w2 = __int_as_float(e2.y), w3 = __int_as_float(e3.y);
                acc.x = fmaf(w0, r0.x, acc.x); acc.y = fmaf(w0, r0.y, acc.y);
                acc.z = fmaf(w0, r0.z, acc.z); acc.w = fmaf(w0, r0.w, acc.w);
                acc.x = fmaf(w1, r1.x, acc.x); acc.y = fmaf(w1, r1.y, acc.y);
                acc.z = fmaf(w1, r1.z, acc.z); acc.w = fmaf(w1, r1.w, acc.w);
                acc.x = fmaf(w2, r2.x, acc.x); acc.y = fmaf(w2, r2.y, acc.y);
                acc.z = fmaf(w2, r2.z, acc.z); acc.w = fmaf(w2, r2.w, acc.w);
                acc.x = fmaf(w3, r3.x, acc.x); acc.y = fmaf(w3, r3.y, acc.y);
                acc.z = fmaf(w3, r3.z, acc.z); acc.w = fmaf(w3, r3.w, acc.w);
            }
            for (; j < cnt; ++j) {
                int2 e = csr[s0 + j];
                float4 r = *(const float4*)&hin[(size_t)e.x * D + c];
                float w = __int_as_float(e.y);
                acc.x = fmaf(w, r.x, acc.x); acc.y = fmaf(w, r.y, acc.y);
                acc.z = fmaf(w, r.z, acc.z); acc.w = fmaf(w, r.w, acc.w);
            }
            // MFMA-permuted + bank-swizzled LDS store
            int idx = s * 128 + (p0 ^ ((s & 7) << 2));
            *(float4*)&sT[idx] = acc;
        }
    }
    __syncthreads();

    // ---- phase 2: split-bf16 MFMA ----
    constexpr int WAVES = THREADS / 64;
    constexpr int WR = (ROWS / 16 < WAVES) ? ROWS / 16 : WAVES;  // row tiles
    constexpr int CG = WAVES / WR;        // col groups (waves per row tile)
    constexpr int NTW = NTT / CG;         // col tiles per wave
    const int w = threadIdx.x >> 6;
    const int lane = threadIdx.x & 63;
    const int q = lane & 15, g = lane >> 4;
    const int rtile = w % WR;
    const int cg = w / WR;
    const int rloc = rtile * 16 + q;
    const int sw = (q & 7) << 2;

    v4f acc[NTW];
#pragma unroll
    for (int nt = 0; nt < NTW; ++nt) acc[nt] = (v4f)0.f;

    const float* rp = &sT[rloc * 128];

#pragma unroll
    for (int ks = 0; ks < 4; ++ks) {
        int o = ks * 32 + g * 8;
        float4 fa = *(const float4*)&rp[o ^ sw];
        float4 fb = *(const float4*)&rp[(o + 4) ^ sw];
        v8s ah, al;
        {
            unsigned short h_, l_;
            f2hl(fa.x, h_, l_); ah[0] = (short)h_; al[0] = (short)l_;
            f2hl(fa.y, h_, l_); ah[1] = (short)h_; al[1] = (short)l_;
            f2hl(fa.z, h_, l_); ah[2] = (short)h_; al[2] = (short)l_;
            f2hl(fa.w, h_, l_); ah[3] = (short)h_; al[3] = (short)l_;
            f2hl(fb.x, h_, l_); ah[4] = (short)h_; al[4] = (short)l_;
            f2hl(fb.y, h_, l_); ah[5] = (short)h_; al[5] = (short)l_;
            f2hl(fb.z, h_, l_); ah[6] = (short)h_; al[6] = (short)l_;
            f2hl(fb.w, h_, l_); ah[7] = (short)h_; al[7] = (short)l_;
        }
        const unsigned int* wk = wf + ((size_t)(ks * NTT + cg * NTW) * 64 + lane) * 8;
#pragma unroll
        for (int nt = 0; nt < NTW; ++nt) {
            v8s wh = *(const v8s*)(wk + nt * 512);
            v8s wl = *(const v8s*)(wk + nt * 512 + 4);
            acc[nt] = __builtin_amdgcn_mfma_f32_16x16x32_bf16(ah, wh, acc[nt], 0, 0, 0);
            acc[nt] = __builtin_amdgcn_mfma_f32_16x16x32_bf16(al, wh, acc[nt], 0, 0, 0);
            acc[nt] = __builtin_amdgcn_mfma_f32_16x16x32_bf16(ah, wl, acc[nt], 0, 0, 0);
        }
    }

    // ---- epilogue: bias (+ReLU), store. C/D layout: col = q, row = 4g + i ----
    const int growb = nb + rtile * 16 + 4 * g;
#pragma unroll
    for (int nt = 0; nt < NTW; ++nt) {
        int col = (cg * NTW + nt) * 16 + q;
        float bv = bias[col];
#pragma unroll
        for (int i = 0; i < 4; ++i) {
            int grow = growb + i;
            if (grow < N) {
                float v = acc[nt][i] + bv;
                if (RELU) v = fmaxf(v, 0.f);
                hout[(size_t)grow * OSTRIDE + col] = v;
            }
        }
    }
}

// ---------------- head: T16 = H @ Wo, then Out = A_norm . T16 + bo ----------------

__global__ __launch_bounds__(256) void k_gemm_out(const float* __restrict__ A,
                                                  const float* __restrict__ Wo,
                                                  float* __restrict__ Out, int M) {
    __shared__ float sW[128 * 16];
    for (int i = threadIdx.x * 4; i < 2048; i += 1024)
        *(float4*)&sW[i] = *(const float4*)&Wo[i];
    __syncthreads();
    int r = blockIdx.x * 16 + (threadIdx.x >> 4);
    int c = threadIdx.x & 15;
    if (r >= M) return;
    const float* arow = A + (size_t)r * D;
    float acc = 0.f;
#pragma unroll
    for (int k4 = 0; k4 < 32; ++k4) {
        float4 h = *(const float4*)&arow[k4 * 4];
        acc = fmaf(h.x, sW[(k4 * 4 + 0) * 16 + c], acc);
        acc = fmaf(h.y, sW[(k4 * 4 + 1) * 16 + c], acc);
        acc = fmaf(h.z, sW[(k4 * 4 + 2) * 16 + c], acc);
        acc = fmaf(h.w, sW[(k4 * 4 + 3) * 16 + c], acc);
    }
    Out[(size_t)r * 16 + c] = acc;
}

__global__ __launch_bounds__(256) void k_aggr_out(const float* __restrict__ T16,
                                                  const int2* __restrict__ csr,
                                                  const int* __restrict__ rowst,
                                                  const int* __restrict__ deg,
                                                  const float* __restrict__ dinv,
                                                  const float* __restrict__ bias,
                                                  float* __restrict__ Out, int N) {
    int node = blockIdx.x * 16 + (threadIdx.x >> 4);
    int c = threadIdx.x & 15;
    if (node >= N) return;
    float di = dinv[node];
    float acc = fmaf(di * di, T16[(size_t)node * 16 + c], bias[c]);
    int s0 = rowst[node];
    int cnt = deg[node];
    int j = 0;
    for (; j + 4 <= cnt; j += 4) {
        int2 e0 = csr[s0 + j + 0];
        int2 e1 = csr[s0 + j + 1];
        int2 e2 = csr[s0 + j + 2];
        int2 e3 = csr[s0 + j + 3];
        float r0 = T16[(size_t)e0.x * 16 + c];
        float r1 = T16[(size_t)e1.x * 16 + c];
        float r2 = T16[(size_t)e2.x * 16 + c];
        float r3 = T16[(size_t)e3.x * 16 + c];
        acc = fmaf(__int_as_float(e0.y), r0, acc);
        acc = fmaf(__int_as_float(e1.y), r1, acc);
        acc = fmaf(__int_as_float(e2.y), r2, acc);
        acc = fmaf(__int_as_float(e3.y), r3, acc);
    }
    for (; j < cnt; ++j) {
        int2 e = csr[s0 + j];
        acc = fmaf(__int_as_float(e.y), T16[(size_t)e.x * 16 + c], acc);
    }
    Out[(size_t)node * 16 + c] = acc;
}

// ---------------- launch ----------------

extern "C" void kernel_launch(void* const* d_in, const int* in_sizes, int n_in,
                              void* d_out, int out_size, void* d_ws, size_t ws_size,
                              hipStream_t stream) {
    const float* x  = (const float*)d_in[0];
    const int*   ei = (const int*)d_in[1];
    const float* Ws = (const float*)d_in[2];
    const float* bs = (const float*)d_in[3];
    const float* Wo = (const float*)d_in[4];
    const float* bo = (const float*)d_in[5];
    float* out = (float*)d_out;

    const int N = in_sizes[0] / D;     // 100000
    const int E = in_sizes[1] / 2;     // 600000
    const int* src = ei;
    const int* dst = ei + E;

    // workspace layout (~109.4 MB)
    float* H0     = (float*)d_ws;                     // N*128 fp32 ping
    float* H1     = H0 + (size_t)N * D;               // N*128 fp32 pong
    int*   deg    = (int*)(H1 + (size_t)N * D);
    int*   cursor = deg + N;
    int*   rowst  = cursor + N;
    float* dinv   = (float*)(rowst + N);
    int*   bsums  = (int*)(dinv + N);
    int2*  csr    = (int2*)(bsums + 1024);
    unsigned int* wfrag = (unsigned int*)(csr + E);   // 9 * 16384 uints (576 KB)

    const int NB = (N + 1023) / 1024;

    hipMemsetAsync(deg, 0, (size_t)2 * N * sizeof(int), stream);  // deg + cursor
    k_count<<<(E + 255) / 256, 256, 0, stream>>>(dst, deg, E);
    k_blocksum<<<NB, 256, 0, stream>>>(deg, bsums, N);
    k_scanbsums<<<1, 256, 0, stream>>>(bsums, NB);
    k_scan2<<<NB, 256, 0, stream>>>(deg, bsums, rowst, dinv, N);
    k_fill<<<(E + 255) / 256, 256, 0, stream>>>(src, dst, rowst, cursor, dinv, csr, E);

    k_wconv<<<288, 64, 0, stream>>>(Ws, wfrag);

    const float* hin = x;
    float* hout = H0;
    const int gblk16 = (N + 15) / 16;
    for (int l = 0; l < 9; ++l) {
        k_fused<128, 16, 8, 1, 128><<<gblk16, 128, 0, stream>>>(hin, csr, rowst, deg,
                                                                dinv,
                                                                wfrag + (size_t)l * 16384,
                                                                bs + (size_t)l * D,
                                                                hout, N);
        hin = hout;
        hout = (hout == H0) ? H1 : H0;
    }
    // head: transform-then-aggregate (16-wide gather, 8x fewer bytes)
    float* T16 = hout;                 // reuse the other ping-pong buffer
    k_gemm_out<<<(N + 15) / 16, 256, 0, stream>>>(hin, Wo, T16, N);
    k_aggr_out<<<(N + 15) / 16, 256, 0, stream>>>(T16, csr, rowst, deg, dinv, bo, out, N);
}

// Round 10
// 803.341 us; speedup vs baseline: 2.0529x; 1.0746x over previous
//
#include <hip/hip_runtime.h>

#define D 128

typedef short v8s __attribute__((ext_vector_type(8)));
typedef float v4f __attribute__((ext_vector_type(4)));

// fp32 -> bf16 hi/lo split: f ~= hi + lo, |err| ~ 2^-17 * |f|
__device__ __forceinline__ void f2hl(float f, unsigned short& h, unsigned short& l) {
    unsigned int u = __float_as_uint(f);
    unsigned int hu = u & 0xffff0000u;
    float lf = f - __uint_as_float(hu);          // exact
    h = (unsigned short)(hu >> 16);
    l = (unsigned short)((__float_as_uint(lf) + 0x8000u) >> 16);  // round
}

// permuted column position for a 4-aligned k chunk (MFMA A-frag contiguous layout)
// k = 4g + (e&3) + 16*(e>>2)  <->  p = 8g + e   (within each 32-wide k block)
__device__ __forceinline__ int permc(int c) {
    return (c & ~31) + ((c & 12) << 1) + ((c & 16) >> 2);
}

// ---------------- preprocessing ----------------

__global__ void k_count(const int* __restrict__ dst, int* __restrict__ deg, int E) {
    int e = blockIdx.x * 256 + threadIdx.x;
    if (e < E) atomicAdd(&deg[dst[e]], 1);
}

__global__ __launch_bounds__(256) void k_blocksum(const int* __restrict__ deg,
                                                  int* __restrict__ bsums, int N) {
    __shared__ int s[256];
    int base = blockIdx.x * 1024 + threadIdx.x * 4;
    int v = 0;
#pragma unroll
    for (int j = 0; j < 4; ++j) { int i = base + j; if (i < N) v += deg[i]; }
    s[threadIdx.x] = v;
    __syncthreads();
    for (int off = 128; off > 0; off >>= 1) {
        if (threadIdx.x < off) s[threadIdx.x] += s[threadIdx.x + off];
        __syncthreads();
    }
    if (threadIdx.x == 0) bsums[blockIdx.x] = s[0];
}

__global__ __launch_bounds__(256) void k_scanbsums(int* __restrict__ bsums, int NB) {
    __shared__ int s[256];
    __shared__ int carry;
    int t = threadIdx.x;
    if (t == 0) carry = 0;
    __syncthreads();
    for (int base = 0; base < NB; base += 256) {
        int i = base + t;
        int v = (i < NB) ? bsums[i] : 0;
        s[t] = v;
        __syncthreads();
        for (int off = 1; off < 256; off <<= 1) {
            int x = (t >= off) ? s[t - off] : 0;
            __syncthreads();
            s[t] += x;
            __syncthreads();
        }
        if (i < NB) bsums[i] = carry + s[t] - v;   // exclusive
        __syncthreads();
        if (t == 0) carry += s[255];
        __syncthreads();
    }
}

__global__ __launch_bounds__(256) void k_scan2(const int* __restrict__ deg,
                                               const int* __restrict__ bsums,
                                               int* __restrict__ rowst,
                                               float* __restrict__ dinv, int N) {
    __shared__ int s[256];
    int t = threadIdx.x;
    int base = blockIdx.x * 1024 + t * 4;
    int v[4];
#pragma unroll
    for (int j = 0; j < 4; ++j) { int i = base + j; v[j] = (i < N) ? deg[i] : 0; }
    int tsum = v[0] + v[1] + v[2] + v[3];
    s[t] = tsum;
    __syncthreads();
    for (int off = 1; off < 256; off <<= 1) {
        int x = (t >= off) ? s[t - off] : 0;
        __syncthreads();
        s[t] += x;
        __syncthreads();
    }
    int run = s[t] - tsum + bsums[blockIdx.x];
#pragma unroll
    for (int j = 0; j < 4; ++j) {
        int i = base + j;
        if (i < N) {
            rowst[i] = run;
            dinv[i] = rsqrtf((float)(v[j] + 1));   // +1 for self-loop
        }
        run += v[j];
    }
}

__global__ void k_fill(const int* __restrict__ src, const int* __restrict__ dst,
                       const int* __restrict__ rowst, int* __restrict__ cursor,
                       const float* __restrict__ dinv, int2* __restrict__ csr, int E) {
    int e = blockIdx.x * 256 + threadIdx.x;
    if (e >= E) return;
    int s = src[e], d = dst[e];
    int p = rowst[d] + atomicAdd(&cursor[d], 1);
    csr[p] = make_int2(s, __float_as_int(dinv[s] * dinv[d]));
}

// ---------------- weight fragment packing ----------------

// Ws[9][128][128] fp32 -> per-lane MFMA B fragments, hi/lo bf16:
// wf[((l*4+ks)*8+nt)*64 + lane][8 words]: words 0-3 = hi frag, 4-7 = lo frag
__global__ __launch_bounds__(64) void k_wconv(const float* __restrict__ Ws,
                                              unsigned int* __restrict__ wf) {
    int b = blockIdx.x;              // l*32 + ks*8 + nt
    int l = b >> 5, ks = (b >> 3) & 3, nt = b & 7;
    int lane = threadIdx.x;
    int g = lane >> 4, c = (lane & 15) + nt * 16;
    const float* W = Ws + (size_t)l * D * D;
    unsigned int hw[4], lw[4];
#pragma unroll
    for (int w = 0; w < 4; ++w) {
        unsigned short hs[2], ls[2];
#pragma unroll
        for (int j = 0; j < 2; ++j) {
            int e = 2 * w + j;
            int k = ks * 32 + 4 * g + (e & 3) + 16 * (e >> 2);
            f2hl(W[k * D + c], hs[j], ls[j]);
        }
        hw[w] = (unsigned int)hs[0] | ((unsigned int)hs[1] << 16);
        lw[w] = (unsigned int)ls[0] | ((unsigned int)ls[1] << 16);
    }
    unsigned int* dstp = wf + ((size_t)((l * 4 + ks) * 8 + nt) * 64 + lane) * 8;
    *(uint4*)dstp = make_uint4(hw[0], hw[1], hw[2], hw[3]);
    *(uint4*)(dstp + 4) = make_uint4(lw[0], lw[1], lw[2], lw[3]);
}

// ---------------- fused hidden layer: hout = relu( (A_norm . hin) @ W + b ) --------
// 16-node tile per 512-thread block. Phase 1: 16 groups of 32 lanes, ONE node per
// group (no multi-node loop -- unbroken unroll-4 load pipeline, the R1-proven walk),
// aggregate into LDS (fp32), MFMA-permuted + XOR-bank-swizzled.
// Phase 2: 8 waves, each one 16x16 col tile: split-bf16 MFMA, bias+ReLU, store.

template <int THREADS, int ROWS, int NTT, int RELU, int OSTRIDE>
__global__ __launch_bounds__(THREADS, 8) void k_fused(const float* __restrict__ hin,
                                                      const int2* __restrict__ csr,
                                                      const int* __restrict__ rowst,
                                                      const int* __restrict__ deg,
                                                      const float* __restrict__ dinv,
                                                      const unsigned int* __restrict__ wf,
                                                      const float* __restrict__ bias,
                                                      float* __restrict__ hout, int N) {
    __shared__ float sT[ROWS * 128];
    const int nb = blockIdx.x * ROWS;

    // ---- phase 1: each 32-lane group aggregates exactly one node ----
    {
        const int s = threadIdx.x >> 5;          // group id == row in tile
        const int l32 = threadIdx.x & 31;
        const int c = l32 << 2;
        const int p0 = permc(c);
        int node = nb + s;
        if (node < N) {
            float di = dinv[node];
            float s2 = di * di;
            float4 t0 = *(const float4*)&hin[(size_t)node * D + c];
            float4 acc;
            acc.x = s2 * t0.x; acc.y = s2 * t0.y;
            acc.z = s2 * t0.z; acc.w = s2 * t0.w;

            int s0 = rowst[node];
            int cnt = deg[node];
            int j = 0;
            for (; j + 4 <= cnt; j += 4) {
                int2 e0 = csr[s0 + j + 0];
                int2 e1 = csr[s0 + j + 1];
                int2 e2 = csr[s0 + j + 2];
                int2 e3 = csr[s0 + j + 3];
                float4 r0 = *(const float4*)&hin[(size_t)e0.x * D + c];
                float4 r1 = *(const float4*)&hin[(size_t)e1.x * D + c];
                float4 r2 = *(const float4*)&hin[(size_t)e2.x * D + c];
                float4 r3 = *(const float4*)&hin[(size_t)e3.x * D + c];
                float w0 = __int_as_float(e0.y), w1 = __int_as_float(e1.y);
                float w2 = __int_as_float(e2.y), w3 = __int_as_float(e3.y);
                acc.x = fmaf(w0, r0.x, acc.x); acc.y = fmaf(w0, r0.y, acc.y);
                acc.z = fmaf(w0, r0.z, acc.z); acc.w = fmaf(w0, r0.w, acc.w);
                acc.x = fmaf(w1, r1.x, acc.x); acc.y = fmaf(w1, r1.y, acc.y);
                acc.z = fmaf(w1, r1.z, acc.z); acc.w = fmaf(w1, r1.w, acc.w);
                acc.x = fmaf(w2, r2.x, acc.x); acc.y = fmaf(w2, r2.y, acc.y);
                acc.z = fmaf(w2, r2.z, acc.z); acc.w = fmaf(w2, r2.w, acc.w);
                acc.x = fmaf(w3, r3.x, acc.x); acc.y = fmaf(w3, r3.y, acc.y);
                acc.z = fmaf(w3, r3.z, acc.z); acc.w = fmaf(w3, r3.w, acc.w);
            }
            for (; j < cnt; ++j) {
                int2 e = csr[s0 + j];
                float4 r = *(const float4*)&hin[(size_t)e.x * D + c];
                float w = __int_as_float(e.y);
                acc.x = fmaf(w, r.x, acc.x); acc.y = fmaf(w, r.y, acc.y);
                acc.z = fmaf(w, r.z, acc.z); acc.w = fmaf(w, r.w, acc.w);
            }
            // MFMA-permuted + bank-swizzled LDS store
            int idx = s * 128 + (p0 ^ ((s & 7) << 2));
            *(float4*)&sT[idx] = acc;
        }
    }
    __syncthreads();

    // ---- phase 2: split-bf16 MFMA ----
    constexpr int WAVES = THREADS / 64;
    constexpr int WR = (ROWS / 16 < WAVES) ? ROWS / 16 : WAVES;  // row tiles
    constexpr int CG = WAVES / WR;        // col groups (waves per row tile)
    constexpr int NTW = NTT / CG;         // col tiles per wave
    const int w = threadIdx.x >> 6;
    const int lane = threadIdx.x & 63;
    const int q = lane & 15, g = lane >> 4;
    const int rtile = w % WR;
    const int cg = w / WR;
    const int rloc = rtile * 16 + q;
    const int sw = (q & 7) << 2;

    v4f acc[NTW];
#pragma unroll
    for (int nt = 0; nt < NTW; ++nt) acc[nt] = (v4f)0.f;

    const float* rp = &sT[rloc * 128];

#pragma unroll
    for (int ks = 0; ks < 4; ++ks) {
        int o = ks * 32 + g * 8;
        float4 fa = *(const float4*)&rp[o ^ sw];
        float4 fb = *(const float4*)&rp[(o + 4) ^ sw];
        v8s ah, al;
        {
            unsigned short h_, l_;
            f2hl(fa.x, h_, l_); ah[0] = (short)h_; al[0] = (short)l_;
            f2hl(fa.y, h_, l_); ah[1] = (short)h_; al[1] = (short)l_;
            f2hl(fa.z, h_, l_); ah[2] = (short)h_; al[2] = (short)l_;
            f2hl(fa.w, h_, l_); ah[3] = (short)h_; al[3] = (short)l_;
            f2hl(fb.x, h_, l_); ah[4] = (short)h_; al[4] = (short)l_;
            f2hl(fb.y, h_, l_); ah[5] = (short)h_; al[5] = (short)l_;
            f2hl(fb.z, h_, l_); ah[6] = (short)h_; al[6] = (short)l_;
            f2hl(fb.w, h_, l_); ah[7] = (short)h_; al[7] = (short)l_;
        }
        const unsigned int* wk = wf + ((size_t)(ks * NTT + cg * NTW) * 64 + lane) * 8;
#pragma unroll
        for (int nt = 0; nt < NTW; ++nt) {
            v8s wh = *(const v8s*)(wk + nt * 512);
            v8s wl = *(const v8s*)(wk + nt * 512 + 4);
            acc[nt] = __builtin_amdgcn_mfma_f32_16x16x32_bf16(ah, wh, acc[nt], 0, 0, 0);
            acc[nt] = __builtin_amdgcn_mfma_f32_16x16x32_bf16(al, wh, acc[nt], 0, 0, 0);
            acc[nt] = __builtin_amdgcn_mfma_f32_16x16x32_bf16(ah, wl, acc[nt], 0, 0, 0);
        }
    }

    // ---- epilogue: bias (+ReLU), store. C/D layout: col = q, row = 4g + i ----
    const int growb = nb + rtile * 16 + 4 * g;
#pragma unroll
    for (int nt = 0; nt < NTW; ++nt) {
        int col = (cg * NTW + nt) * 16 + q;
        float bv = bias[col];
#pragma unroll
        for (int i = 0; i < 4; ++i) {
            int grow = growb + i;
            if (grow < N) {
                float v = acc[nt][i] + bv;
                if (RELU) v = fmaxf(v, 0.f);
                hout[(size_t)grow * OSTRIDE + col] = v;
            }
        }
    }
}

// ---------------- head: T16 = H @ Wo, then Out = A_norm . T16 + bo ----------------

__global__ __launch_bounds__(256) void k_gemm_out(const float* __restrict__ A,
                                                  const float* __restrict__ Wo,
                                                  float* __restrict__ Out, int M) {
    __shared__ float sW[128 * 16];
    for (int i = threadIdx.x * 4; i < 2048; i += 1024)
        *(float4*)&sW[i] = *(const float4*)&Wo[i];
    __syncthreads();
    int r = blockIdx.x * 16 + (threadIdx.x >> 4);
    int c = threadIdx.x & 15;
    if (r >= M) return;
    const float* arow = A + (size_t)r * D;
    float acc = 0.f;
#pragma unroll
    for (int k4 = 0; k4 < 32; ++k4) {
        float4 h = *(const float4*)&arow[k4 * 4];
        acc = fmaf(h.x, sW[(k4 * 4 + 0) * 16 + c], acc);
        acc = fmaf(h.y, sW[(k4 * 4 + 1) * 16 + c], acc);
        acc = fmaf(h.z, sW[(k4 * 4 + 2) * 16 + c], acc);
        acc = fmaf(h.w, sW[(k4 * 4 + 3) * 16 + c], acc);
    }
    Out[(size_t)r * 16 + c] = acc;
}

__global__ __launch_bounds__(256) void k_aggr_out(const float* __restrict__ T16,
                                                  const int2* __restrict__ csr,
                                                  const int* __restrict__ rowst,
                                                  const int* __restrict__ deg,
                                                  const float* __restrict__ dinv,
                                                  const float* __restrict__ bias,
                                                  float* __restrict__ Out, int N) {
    int node = blockIdx.x * 16 + (threadIdx.x >> 4);
    int c = threadIdx.x & 15;
    if (node >= N) return;
    float di = dinv[node];
    float acc = fmaf(di * di, T16[(size_t)node * 16 + c], bias[c]);
    int s0 = rowst[node];
    int cnt = deg[node];
    int j = 0;
    for (; j + 4 <= cnt; j += 4) {
        int2 e0 = csr[s0 + j + 0];
        int2 e1 = csr[s0 + j + 1];
        int2 e2 = csr[s0 + j + 2];
        int2 e3 = csr[s0 + j + 3];
        float r0 = T16[(size_t)e0.x * 16 + c];
        float r1 = T16[(size_t)e1.x * 16 + c];
        float r2 = T16[(size_t)e2.x * 16 + c];
        float r3 = T16[(size_t)e3.x * 16 + c];
        acc = fmaf(__int_as_float(e0.y), r0, acc);
        acc = fmaf(__int_as_float(e1.y), r1, acc);
        acc = fmaf(__int_as_float(e2.y), r2, acc);
        acc = fmaf(__int_as_float(e3.y), r3, acc);
    }
    for (; j < cnt; ++j) {
        int2 e = csr[s0 + j];
        acc = fmaf(__int_as_float(e.y), T16[(size_t)e.x * 16 + c], acc);
    }
    Out[(size_t)node * 16 + c] = acc;
}

// ---------------- launch ----------------

extern "C" void kernel_launch(void* const* d_in, const int* in_sizes, int n_in,
                              void* d_out, int out_size, void* d_ws, size_t ws_size,
                              hipStream_t stream) {
    const float* x  = (const float*)d_in[0];
    const int*   ei = (const int*)d_in[1];
    const float* Ws = (const float*)d_in[2];
    const float* bs = (const float*)d_in[3];
    const float* Wo = (const float*)d_in[4];
    const float* bo = (const float*)d_in[5];
    float* out = (float*)d_out;

    const int N = in_sizes[0] / D;     // 100000
    const int E = in_sizes[1] / 2;     // 600000
    const int* src = ei;
    const int* dst = ei + E;

    // workspace layout (~109.4 MB)
    float* H0     = (float*)d_ws;                     // N*128 fp32 ping
    float* H1     = H0 + (size_t)N * D;               // N*128 fp32 pong
    int*   deg    = (int*)(H1 + (size_t)N * D);
    int*   cursor = deg + N;
    int*   rowst  = cursor + N;
    float* dinv   = (float*)(rowst + N);
    int*   bsums  = (int*)(dinv + N);
    int2*  csr    = (int2*)(bsums + 1024);
    unsigned int* wfrag = (unsigned int*)(csr + E);   // 9 * 16384 uints (576 KB)

    const int NB = (N + 1023) / 1024;

    hipMemsetAsync(deg, 0, (size_t)2 * N * sizeof(int), stream);  // deg + cursor
    k_count<<<(E + 255) / 256, 256, 0, stream>>>(dst, deg, E);
    k_blocksum<<<NB, 256, 0, stream>>>(deg, bsums, N);
    k_scanbsums<<<1, 256, 0, stream>>>(bsums, NB);
    k_scan2<<<NB, 256, 0, stream>>>(deg, bsums, rowst, dinv, N);
    k_fill<<<(E + 255) / 256, 256, 0, stream>>>(src, dst, rowst, cursor, dinv, csr, E);

    k_wconv<<<288, 64, 0, stream>>>(Ws, wfrag);

    const float* hin = x;
    float* hout = H0;
    const int gblk16 = (N + 15) / 16;
    for (int l = 0; l < 9; ++l) {
        k_fused<512, 16, 8, 1, 128><<<gblk16, 512, 0, stream>>>(hin, csr, rowst, deg,
                                                                dinv,
                                                                wfrag + (size_t)l * 16384,
                                                                bs + (size_t)l * D,
                                                                hout, N);
        hin = hout;
        hout = (hout == H0) ? H1 : H0;
    }
    // head: transform-then-aggregate (16-wide gather, 8x fewer bytes)
    float* T16 = hout;                 // reuse the other ping-pong buffer
    k_gemm_out<<<(N + 15) / 16, 256, 0, stream>>>(hin, Wo, T16, N);
    k_aggr_out<<<(N + 15) / 16, 256, 0, stream>>>(T16, csr, rowst, deg, dinv, bo, out, N);
}